// Round 6
// baseline (189.190 us; speedup 1.0000x reference)
//
#include <hip/hip_runtime.h>
#include <math.h>

// Problem constants
#define B_    8
#define C_    192
#define N_    3136          // H*W
#define K_    9
#define C2_   384
#define OUT_  192
#define M_    (B_ * N_)     // 25088 rows
#define EPS_  1e-5f

typedef __bf16 bf16;
typedef __bf16 bf16x2 __attribute__((ext_vector_type(2)));
typedef __bf16 bf16x8 __attribute__((ext_vector_type(8)));
typedef float  f32x4  __attribute__((ext_vector_type(4)));

__device__ __forceinline__ float gelu_f(float x) {
    return 0.5f * x * (1.0f + erff(x * 0.70710678118654752440f));
}

// async global->LDS, 16B per lane; lds base must be wave-uniform
__device__ __forceinline__ void gl_lds16(const void* g, void* l) {
    __builtin_amdgcn_global_load_lds(
        (const __attribute__((address_space(1))) unsigned int*)g,
        (__attribute__((address_space(3))) unsigned int*)l, 16, 0, 0);
}

// Swizzled LDS tile layout: tile is [rows][64] bf16, stored as 16B chunks.
// Logical chunk (r, c8) lives at slot r*8 + (c8 ^ (r&7)); element offset slot*8.
// Conversely slot s holds logical chunk c8 = (s&7) ^ ((s>>3)&7).
__device__ __forceinline__ int sw_off(int r, int c8) {
    return (r * 8 + (c8 ^ (r & 7))) * 8;
}

// ---------------------------------------------------------------------------
// k_pre: z<8 -> transpose x fp32 [B,C,N] -> xt bf16 [B,N,C]
//        z==8 -> cast+permute w1 -> w1p, cast w2 -> w2b, zero stats
// grid (49, 6, 9), block 256
__global__ __launch_bounds__(256) void k_pre(const float* __restrict__ x,
                                             bf16* __restrict__ xt,
                                             const float* __restrict__ w1,
                                             const float* __restrict__ w2,
                                             bf16* __restrict__ w1p,
                                             bf16* __restrict__ w2b,
                                             float* __restrict__ stats) {
    if (blockIdx.z == 8) {
        const int bid = blockIdx.y * 49 + blockIdx.x;        // 0..293
        #pragma unroll
        for (int t = 0; t < 2; ++t) {
            const int idx = bid * 512 + t * 256 + threadIdx.x;
            if (idx < C2_ * C2_) {
                const int o  = idx / C2_;
                const int cc = idx - o * C2_;
                const int src = (cc < C_) ? (2 * cc) : (2 * (cc - C_) + 1);
                w1p[idx] = (bf16)w1[o * C2_ + src];
            }
            if (idx < OUT_ * C2_) w2b[idx] = (bf16)w2[idx];
            if (idx < 1152) stats[idx] = 0.f;   // p1s[384] p1q[384] p2s[192] p2q[192]
        }
        return;
    }
    __shared__ float T[32][65];
    const int b  = blockIdx.z;
    const int c0 = blockIdx.y * 32;
    const int n0 = blockIdx.x * 64;
    const int tid = threadIdx.x;
    {
        const int nl = tid & 63;
        const int cl = tid >> 6;
        #pragma unroll
        for (int r = 0; r < 8; ++r) {
            const int c = cl + r * 4;
            T[c][nl] = x[((size_t)b * C_ + (c0 + c)) * N_ + n0 + nl];
        }
    }
    __syncthreads();
    {
        const int cl = tid & 31;
        const int nl = tid >> 5;
        #pragma unroll
        for (int r = 0; r < 8; ++r) {
            const int n = nl + r * 8;
            xt[((size_t)b * N_ + n0 + n) * C_ + c0 + cl] = (bf16)T[cl][n];
        }
    }
}

// ---------------------------------------------------------------------------
// Feats (diff half): d[node][c] = max_k( xt[j_k][c] - xt[i_k][c] )
// 2 nodes per block, bf16x2 per thread (channel pairs). grid M/2, block 192
__global__ __launch_bounds__(192) void k_feats(const bf16* __restrict__ xt,
                                               const int* __restrict__ eidx,
                                               bf16* __restrict__ dbuf) {
    const int t    = threadIdx.x;
    const int half = (t >= 96) ? 1 : 0;
    const int cp   = t - half * 96;                  // 0..95 -> channels 2cp,2cp+1
    const int node = blockIdx.x * 2 + half;
    const int b    = node / N_;
    const int* e0 = eidx + (size_t)node * K_;
    const int* e1 = e0 + (size_t)M_ * K_;
    const bf16* xb = xt + (size_t)b * N_ * C_;
    float mx0 = -1e30f, mx1 = -1e30f;
    #pragma unroll
    for (int k = 0; k < K_; ++k) {
        const int j = e0[k];
        const int i = e1[k];
        const bf16x2 aj = *(const bf16x2*)&xb[(size_t)j * C_ + 2 * cp];
        const bf16x2 ai = *(const bf16x2*)&xb[(size_t)i * C_ + 2 * cp];
        mx0 = fmaxf(mx0, (float)aj[0] - (float)ai[0]);
        mx1 = fmaxf(mx1, (float)aj[1] - (float)ai[1]);
    }
    bf16x2 o; o[0] = (bf16)mx0; o[1] = (bf16)mx1;
    *(bf16x2*)&dbuf[(size_t)node * C_ + 2 * cp] = o;
}

// ---------------------------------------------------------------------------
// GEMM1: h1[m,o] = sum_c [X|D][m,c] * w1p[o,c] + b1[o] -> bf16, fused stats
// 128x128 tile, BK=64, swizzled LDS, 4 waves x (4x4) 16x16x32 frags
// grid (196, 3), block 256
__global__ __launch_bounds__(256) void k_gemm1(const bf16* __restrict__ X,
                                               const bf16* __restrict__ D,
                                               const bf16* __restrict__ Wp,
                                               const float* __restrict__ bias,
                                               bf16* __restrict__ H1,
                                               float* __restrict__ psum,
                                               float* __restrict__ psq) {
    __shared__ bf16 As[128 * 64];
    __shared__ bf16 Bs[128 * 64];
    const int tid  = threadIdx.x;
    const int lane = tid & 63;
    const int wv   = tid >> 6;
    const int l16  = lane & 15;
    const int quad = lane >> 4;
    const int m0   = blockIdx.x * 128;
    const int n0   = blockIdx.y * 128;
    const int wm   = (wv & 1) * 64;
    const int wn   = (wv >> 1) * 64;

    f32x4 acc[4][4] = {};

    for (int kk = 0; kk < C2_; kk += 64) {
        __syncthreads();
        const bf16* asrc = (kk < C_) ? X : D;
        const int   acol = (kk < C_) ? kk : (kk - C_);
        #pragma unroll
        for (int i = 0; i < 4; ++i) {
            const int qb = wv * 256 + i * 64;          // wave-uniform chunk base
            const int q  = qb + lane;
            const int r  = q >> 3;
            const int c8 = (q & 7) ^ (r & 7);          // logical chunk for this slot
            gl_lds16(asrc + (size_t)(m0 + r) * C_ + acol + c8 * 8, &As[qb * 8]);
            gl_lds16(Wp   + (size_t)(n0 + r) * C2_ + kk  + c8 * 8, &Bs[qb * 8]);
        }
        __syncthreads();
        #pragma unroll
        for (int ks = 0; ks < 2; ++ks) {
            bf16x8 af[4], bfr[4];
            #pragma unroll
            for (int f = 0; f < 4; ++f) {
                af[f]  = *(const bf16x8*)&As[sw_off(wm + f * 16 + l16, ks * 4 + quad)];
                bfr[f] = *(const bf16x8*)&Bs[sw_off(wn + f * 16 + l16, ks * 4 + quad)];
            }
            #pragma unroll
            for (int mf = 0; mf < 4; ++mf)
                #pragma unroll
                for (int nf = 0; nf < 4; ++nf)
                    acc[mf][nf] = __builtin_amdgcn_mfma_f32_16x16x32_bf16(
                        af[mf], bfr[nf], acc[mf][nf], 0, 0, 0);
        }
    }

    #pragma unroll
    for (int nf = 0; nf < 4; ++nf) {
        const int col = n0 + wn + nf * 16 + l16;
        const float bv = bias[col];
        float s = 0.f, q = 0.f;
        #pragma unroll
        for (int mf = 0; mf < 4; ++mf) {
            #pragma unroll
            for (int r = 0; r < 4; ++r) {
                const float v = acc[mf][nf][r] + bv;
                s += v; q += v * v;
                H1[(size_t)(m0 + wm + mf * 16 + quad * 4 + r) * C2_ + col] = (bf16)v;
            }
        }
        s += __shfl_xor(s, 16); s += __shfl_xor(s, 32);
        q += __shfl_xor(q, 16); q += __shfl_xor(q, 32);
        if (quad == 0) { atomicAdd(&psum[col], s); atomicAdd(&psq[col], q); }
    }
}

// ---------------------------------------------------------------------------
// GEMM2 with BN1+GELU applied IN LDS once per staged A tile (k_act fused away):
// h2[m,o] = sum_c gelu(bn1(h1[m,c])) * w2[o,c] + b2[o] -> bf16, fused stats
// 128x64 tile, BK=64, swizzled LDS, 4 waves x (4x2) frags
// grid (196, 3), block 256
__global__ __launch_bounds__(256) void k_gemm2(const bf16* __restrict__ H1,
                                               const bf16* __restrict__ W2,
                                               const float* __restrict__ bias,
                                               const float* __restrict__ p1s,
                                               const float* __restrict__ p1q,
                                               const float* __restrict__ g1,
                                               const float* __restrict__ beta1,
                                               bf16* __restrict__ H2,
                                               float* __restrict__ psum,
                                               float* __restrict__ psq) {
    __shared__ bf16 As[128 * 64];
    __shared__ bf16 Bs[64 * 64];
    __shared__ float s_sc[C2_], s_sh[C2_];
    const int tid  = threadIdx.x;
    const int lane = tid & 63;
    const int wv   = tid >> 6;
    const int l16  = lane & 15;
    const int quad = lane >> 4;
    const int m0   = blockIdx.x * 128;
    const int n0   = blockIdx.y * 64;
    const int wm   = (wv & 1) * 64;
    const int wn   = (wv >> 1) * 32;

    // BN1 params once per block (coalesced broadcast loads, 384 rsqrt)
    for (int c = tid; c < C2_; c += 256) {
        const float mean = p1s[c] * (1.0f / (float)M_);
        const float var  = p1q[c] * (1.0f / (float)M_) - mean * mean;
        const float inv  = rsqrtf(var + EPS_);
        const float scl  = g1[c] * inv;
        s_sc[c] = scl;
        s_sh[c] = beta1[c] - mean * scl;
    }

    f32x4 acc[4][2] = {};

    for (int kk = 0; kk < C2_; kk += 64) {
        __syncthreads();
        #pragma unroll
        for (int i = 0; i < 4; ++i) {
            const int qb = wv * 256 + i * 64;
            const int q  = qb + lane;
            const int r  = q >> 3;
            const int c8 = (q & 7) ^ (r & 7);
            gl_lds16(H1 + (size_t)(m0 + r) * C2_ + kk + c8 * 8, &As[qb * 8]);
        }
        #pragma unroll
        for (int i = 0; i < 2; ++i) {
            const int qb = wv * 128 + i * 64;
            const int q  = qb + lane;
            const int r  = q >> 3;
            const int c8 = (q & 7) ^ (r & 7);
            gl_lds16(W2 + (size_t)(n0 + r) * C2_ + kk + c8 * 8, &Bs[qb * 8]);
        }
        __syncthreads();
        // Transform A tile in place: each thread owns 4 of the 1024 slots.
        #pragma unroll
        for (int i = 0; i < 4; ++i) {
            const int s  = tid + i * 256;
            const int r  = s >> 3;
            const int c8 = (s & 7) ^ (r & 7);      // logical chunk held in slot s
            const int cb = kk + c8 * 8;            // base channel of this chunk
            bf16x8 v = *(const bf16x8*)&As[s * 8];
            #pragma unroll
            for (int j = 0; j < 8; ++j) {
                const float y = fmaf((float)v[j], s_sc[cb + j], s_sh[cb + j]);
                v[j] = (bf16)gelu_f(y);
            }
            *(bf16x8*)&As[s * 8] = v;
        }
        __syncthreads();
        #pragma unroll
        for (int ks = 0; ks < 2; ++ks) {
            bf16x8 af[4], bfr[2];
            #pragma unroll
            for (int f = 0; f < 4; ++f)
                af[f] = *(const bf16x8*)&As[sw_off(wm + f * 16 + l16, ks * 4 + quad)];
            #pragma unroll
            for (int f = 0; f < 2; ++f)
                bfr[f] = *(const bf16x8*)&Bs[sw_off(wn + f * 16 + l16, ks * 4 + quad)];
            #pragma unroll
            for (int mf = 0; mf < 4; ++mf)
                #pragma unroll
                for (int nf = 0; nf < 2; ++nf)
                    acc[mf][nf] = __builtin_amdgcn_mfma_f32_16x16x32_bf16(
                        af[mf], bfr[nf], acc[mf][nf], 0, 0, 0);
        }
    }

    #pragma unroll
    for (int nf = 0; nf < 2; ++nf) {
        const int col = n0 + wn + nf * 16 + l16;
        const float bv = bias[col];
        float s = 0.f, q = 0.f;
        #pragma unroll
        for (int mf = 0; mf < 4; ++mf) {
            #pragma unroll
            for (int r = 0; r < 4; ++r) {
                const float v = acc[mf][nf][r] + bv;
                s += v; q += v * v;
                H2[(size_t)(m0 + wm + mf * 16 + quad * 4 + r) * OUT_ + col] = (bf16)v;
            }
        }
        s += __shfl_xor(s, 16); s += __shfl_xor(s, 32);
        q += __shfl_xor(q, 16); q += __shfl_xor(q, 32);
        if (quad == 0) { atomicAdd(&psum[col], s); atomicAdd(&psq[col], q); }
    }
}

// ---------------------------------------------------------------------------
// Output: BN2+GELU + transpose [M,OUT] bf16 -> [B,OUT,N] fp32
// grid (N/64, OUT/32, B), block 256
__global__ __launch_bounds__(256) void k_out(const bf16* __restrict__ H2,
                                             const float* __restrict__ p2s,
                                             const float* __restrict__ p2q,
                                             const float* __restrict__ g,
                                             const float* __restrict__ beta,
                                             float* __restrict__ out) {
    __shared__ float T[64][33];
    const int b  = blockIdx.z;
    const int o0 = blockIdx.y * 32;
    const int n0 = blockIdx.x * 64;
    const int tid = threadIdx.x;
    {
        const int ol = tid & 31;
        const int nl = tid >> 5;
        const int o  = o0 + ol;
        const float mean  = p2s[o] * (1.0f / (float)M_);
        const float var   = p2q[o] * (1.0f / (float)M_) - mean * mean;
        const float inv   = rsqrtf(var + EPS_);
        const float scale = g[o] * inv;
        const float shift = beta[o] - mean * scale;
        #pragma unroll
        for (int r = 0; r < 8; ++r) {
            const int n = nl + r * 8;
            const float v = (float)H2[((size_t)b * N_ + n0 + n) * OUT_ + o];
            T[n][ol] = gelu_f(fmaf(v, scale, shift));
        }
    }
    __syncthreads();
    {
        const int nl = tid & 63;
        const int ol = tid >> 6;
        #pragma unroll
        for (int r = 0; r < 8; ++r) {
            const int o = ol + r * 4;
            out[((size_t)b * OUT_ + o0 + o) * N_ + n0 + nl] = T[nl][o];
        }
    }
}

// ---------------------------------------------------------------------------
extern "C" void kernel_launch(void* const* d_in, const int* in_sizes, int n_in,
                              void* d_out, int out_size, void* d_ws, size_t ws_size,
                              hipStream_t stream) {
    const float* x     = (const float*)d_in[0];
    const int*   eidx  = (const int*)  d_in[1];
    const float* w1    = (const float*)d_in[2];
    const float* b1    = (const float*)d_in[3];
    const float* g1    = (const float*)d_in[4];
    const float* beta1 = (const float*)d_in[5];
    const float* w2    = (const float*)d_in[6];
    const float* b2    = (const float*)d_in[7];
    const float* g2    = (const float*)d_in[8];
    const float* beta2 = (const float*)d_in[9];
    float* out = (float*)d_out;

    char* ws = (char*)d_ws;
    size_t off = 0;
    bf16*  xt    = (bf16*)(ws + off); off += (size_t)M_ * C_  * sizeof(bf16);
    bf16*  dbuf  = (bf16*)(ws + off); off += (size_t)M_ * C_  * sizeof(bf16);
    bf16*  h1    = (bf16*)(ws + off); off += (size_t)M_ * C2_ * sizeof(bf16);
    bf16*  h2    = (bf16*)(ws + off); off += (size_t)M_ * OUT_ * sizeof(bf16);
    bf16*  w1p   = (bf16*)(ws + off); off += (size_t)C2_ * C2_ * sizeof(bf16);
    bf16*  w2b   = (bf16*)(ws + off); off += (size_t)OUT_ * C2_ * sizeof(bf16);
    float* stats = (float*)(ws + off); off += 1152 * sizeof(float);
    float* p1s = stats;        // 384
    float* p1q = stats + 384;  // 384
    float* p2s = stats + 768;  // 192
    float* p2q = stats + 960;  // 192

    k_pre<<<dim3(N_ / 64, C_ / 32, B_ + 1), 256, 0, stream>>>(x, xt, w1, w2, w1p, w2b, stats);
    k_feats<<<M_ / 2, 192, 0, stream>>>(xt, eidx, dbuf);
    k_gemm1<<<dim3(M_ / 128, C2_ / 128), 256, 0, stream>>>(xt, dbuf, w1p, b1, h1, p1s, p1q);
    k_gemm2<<<dim3(M_ / 128, OUT_ / 64), 256, 0, stream>>>(h1, w2b, b2, p1s, p1q, g1, beta1,
                                                           h2, p2s, p2q);
    k_out<<<dim3(N_ / 64, OUT_ / 32, B_), 256, 0, stream>>>(h2, p2s, p2q, g2, beta2, out);
}